// Round 4
// baseline (1452.372 us; speedup 1.0000x reference)
//
#include <hip/hip_runtime.h>
#include <hip/hip_bf16.h>

#define NRES 768
#define CZ   128
#define NPIX (NRES * NRES)

typedef __bf16 bf16x8 __attribute__((ext_vector_type(8)));
typedef float  f32x4  __attribute__((ext_vector_type(4)));
typedef unsigned long long u64;

__device__ __forceinline__ unsigned short f2bf(float f) {
    unsigned u = __float_as_uint(f);
    u += 0x7FFFu + ((u >> 16) & 1u);   // round-to-nearest-even
    return (unsigned short)(u >> 16);
}
__device__ __forceinline__ float bf2f(unsigned short s) {
    return __uint_as_float(((unsigned)s) << 16);
}
__device__ __forceinline__ float sigm(float x) { return 1.0f / (1.0f + __expf(-x)); }
__device__ __forceinline__ f32x4 fzero() { f32x4 z = {0.f, 0.f, 0.f, 0.f}; return z; }

// global -> LDS direct DMA, 16B/lane. LDS dest is wave-uniform base; HW adds lane*16.
typedef __attribute__((address_space(3))) unsigned int       lds_u32;
typedef const __attribute__((address_space(1))) unsigned int glb_u32;
__device__ __forceinline__ void async16(void* lds, const void* g) {
    __builtin_amdgcn_global_load_lds((glb_u32*)g, (lds_u32*)lds, 16, 0, 0);
}

// ---------------------------------------------------------------------------
// Pack weights to bf16. Wcat rows: [0,256)=proj, [256,512)=gate, [512,640)=gl.
__global__ void k_pack(const float* __restrict__ pw, const float* __restrict__ gw,
                       const float* __restrict__ glw, const float* __restrict__ pb,
                       const float* __restrict__ gb, const float* __restrict__ glb,
                       const float* __restrict__ ow,
                       unsigned short* __restrict__ Wcat, float* __restrict__ bcat,
                       unsigned short* __restrict__ Wout) {
    int idx = blockIdx.x * 256 + threadIdx.x;
    if (idx < 640 * 128) {
        int row = idx >> 7;
        float v = (row < 256) ? pw[idx] : (row < 512) ? gw[idx - 256 * 128] : glw[idx - 512 * 128];
        Wcat[idx] = f2bf(v);
    }
    if (idx < 128 * 128) Wout[idx] = f2bf(ow[idx]);
    if (idx < 640) bcat[idx] = (idx < 256) ? pb[idx] : (idx < 512) ? gb[idx - 256] : glb[idx - 512];
}

// ---------------------------------------------------------------------------
// Kernel LN: streaming LayerNorm act(f32) -> actln(bf16), [NPIX][128].
// No LDS, no barriers. 4 lanes/row, 64 rows/block.
__global__ void __launch_bounds__(256)
k_ln(const float* __restrict__ act, const float* __restrict__ lnw,
     const float* __restrict__ lnb, unsigned short* __restrict__ actln) {
    const int t = threadIdx.x;
    const int r = t >> 2, q = t & 3;
    const size_t row = (size_t)blockIdx.x * 64 + r;
    const float* src = act + row * CZ + q * 32;
    float x[32];
    float s = 0.f, s2 = 0.f;
#pragma unroll
    for (int jj = 0; jj < 8; ++jj) {
        f32x4 v = *(const f32x4*)(src + jj * 4);
#pragma unroll
        for (int e = 0; e < 4; ++e) { x[jj * 4 + e] = v[e]; s += v[e]; s2 += v[e] * v[e]; }
    }
    s += __shfl_xor(s, 1);  s2 += __shfl_xor(s2, 1);
    s += __shfl_xor(s, 2);  s2 += __shfl_xor(s2, 2);
    const float mu = s * (1.f / 128.f);
    const float rstd = rsqrtf(s2 * (1.f / 128.f) - mu * mu + 1e-5f);
    unsigned pk[16];
#pragma unroll
    for (int jj = 0; jj < 16; ++jj) {
        const int c = q * 32 + jj * 2;
        const float y0 = (x[jj * 2 + 0] - mu) * rstd * lnw[c]     + lnb[c];
        const float y1 = (x[jj * 2 + 1] - mu) * rstd * lnw[c + 1] + lnb[c + 1];
        pk[jj] = (unsigned)f2bf(y0) | ((unsigned)f2bf(y1) << 16);
    }
    uint4* dst = (uint4*)(actln + row * CZ + q * 32);
#pragma unroll
    for (int p = 0; p < 4; ++p) {
        uint4 u; u.x = pk[4*p]; u.y = pk[4*p+1]; u.z = pk[4*p+2]; u.w = pk[4*p+3];
        dst[p] = u;
    }
}

// ---------------------------------------------------------------------------
// Kernel P: wave-autonomous projection GEMM. Zero LDS, zero barriers.
// Block = 256 thr (4 waves); m-tile = 32 rows; group g: 0=left, 1=right, 2=glin.
// Wave w owns 32 cols of the group's 128. A/B frags read directly from global
// (NT layout, L1 serves intra-block A reuse, L2 serves the 160KB weights).
// Outputs transposed [ch][NPIX] bf16 via 8B-packed stores (4 consecutive m/lane).
__global__ void __launch_bounds__(256, 3)
k_proj(const unsigned short* __restrict__ actln, const float* __restrict__ mask,
       const unsigned short* __restrict__ Wcat, const float* __restrict__ bcat,
       unsigned short* __restrict__ left_t, unsigned short* __restrict__ right_t,
       unsigned short* __restrict__ gate_t) {
    const int t = threadIdx.x, lane = t & 63, w = t >> 6;
    const int bx = blockIdx.x;
    const int mt = bx / 3, g = bx - mt * 3;
    const int m0 = mt * 32;
    const int l15 = lane & 15, l4 = lane >> 4;
    const int col0 = w * 32;

    bf16x8 a[2][4];
#pragma unroll
    for (int f = 0; f < 2; ++f)
#pragma unroll
        for (int kk = 0; kk < 4; ++kk)
            a[f][kk] = *(const bf16x8*)&actln[(size_t)(m0 + f * 16 + l15) * CZ + kk * 32 + l4 * 8];

    if (g < 2) {
        f32x4 mk[2];
#pragma unroll
        for (int f = 0; f < 2; ++f) mk[f] = *(const f32x4*)&mask[m0 + f * 16 + l4 * 4];
        const int wp0 = g * 128 + col0, wg0 = 256 + g * 128 + col0;
        bf16x8 bp[2][4], bg[2][4];
#pragma unroll
        for (int n = 0; n < 2; ++n)
#pragma unroll
            for (int kk = 0; kk < 4; ++kk) {
                bp[n][kk] = *(const bf16x8*)&Wcat[(size_t)(wp0 + n * 16 + l15) * CZ + kk * 32 + l4 * 8];
                bg[n][kk] = *(const bf16x8*)&Wcat[(size_t)(wg0 + n * 16 + l15) * CZ + kk * 32 + l4 * 8];
            }
        f32x4 ap[2][2], ag[2][2];
#pragma unroll
        for (int f = 0; f < 2; ++f)
#pragma unroll
            for (int n = 0; n < 2; ++n) { ap[f][n] = fzero(); ag[f][n] = fzero(); }
#pragma unroll
        for (int kk = 0; kk < 4; ++kk)
#pragma unroll
            for (int f = 0; f < 2; ++f)
#pragma unroll
                for (int n = 0; n < 2; ++n) {
                    ap[f][n] = __builtin_amdgcn_mfma_f32_16x16x32_bf16(a[f][kk], bp[n][kk], ap[f][n], 0, 0, 0);
                    ag[f][n] = __builtin_amdgcn_mfma_f32_16x16x32_bf16(a[f][kk], bg[n][kk], ag[f][n], 0, 0, 0);
                }
        unsigned short* dst = (g == 0) ? left_t : right_t;
#pragma unroll
        for (int f = 0; f < 2; ++f)
#pragma unroll
            for (int n = 0; n < 2; ++n) {
                const int chin = col0 + n * 16 + l15;
                const float pb_ = bcat[g * 128 + chin];
                const float gb_ = bcat[256 + g * 128 + chin];
                u64 pk = 0;
#pragma unroll
                for (int r = 0; r < 4; ++r) {
                    const float val = mk[f][r] * (ap[f][n][r] + pb_) * sigm(ag[f][n][r] + gb_);
                    pk |= (u64)f2bf(val) << (16 * r);
                }
                *(u64*)&dst[(size_t)chin * NPIX + m0 + f * 16 + l4 * 4] = pk;
            }
    } else {
        const int wb0 = 512 + col0;
        bf16x8 bb[2][4];
#pragma unroll
        for (int n = 0; n < 2; ++n)
#pragma unroll
            for (int kk = 0; kk < 4; ++kk)
                bb[n][kk] = *(const bf16x8*)&Wcat[(size_t)(wb0 + n * 16 + l15) * CZ + kk * 32 + l4 * 8];
        f32x4 ac[2][2];
#pragma unroll
        for (int f = 0; f < 2; ++f)
#pragma unroll
            for (int n = 0; n < 2; ++n) ac[f][n] = fzero();
#pragma unroll
        for (int kk = 0; kk < 4; ++kk)
#pragma unroll
            for (int f = 0; f < 2; ++f)
#pragma unroll
                for (int n = 0; n < 2; ++n)
                    ac[f][n] = __builtin_amdgcn_mfma_f32_16x16x32_bf16(a[f][kk], bb[n][kk], ac[f][n], 0, 0, 0);
#pragma unroll
        for (int f = 0; f < 2; ++f)
#pragma unroll
            for (int n = 0; n < 2; ++n) {
                const int chin = col0 + n * 16 + l15;
                const float b_ = bcat[512 + chin];
                u64 pk = 0;
#pragma unroll
                for (int r = 0; r < 4; ++r)
                    pk |= (u64)f2bf(sigm(ac[f][n][r] + b_)) << (16 * r);
                *(u64*)&gate_t[(size_t)chin * NPIX + m0 + f * 16 + l4 * 4] = pk;
            }
    }
}

// ---------------------------------------------------------------------------
// Kernel B: per-channel NT GEMM tri_c = L_c * R_c^T.
// 128x128 tile, BK=64, 4 waves, 2-phase prefetch, source-side chunk-XOR swizzle.
__global__ void __launch_bounds__(256)
k_tri(const unsigned short* __restrict__ left_t,
      const unsigned short* __restrict__ right_t,
      unsigned short* __restrict__ tri) {
    __shared__ unsigned short sA[2][128 * 64];
    __shared__ unsigned short sB[2][128 * 64];

    const int t = threadIdx.x, lane = t & 63, w = t >> 6;
    const int bx = blockIdx.x;                  // 4608 = 8 XCD * 16 ch * 36 tiles
    const int xcd = bx & 7, slot = bx >> 3;
    const int c = xcd + 8 * (slot / 36);
    const int tile = slot % 36;
    const int ti = tile / 6, tj = tile % 6;

    const unsigned short* Lc = left_t  + (size_t)c * NPIX + (size_t)(ti * 128) * NRES;
    const unsigned short* Rc = right_t + (size_t)c * NPIX + (size_t)(tj * 128) * NRES;
    unsigned short* Tc = tri + (size_t)c * NPIX;

    const int wm = w >> 1, wn = w & 1;
    const int l15 = lane & 15, l4 = lane >> 4;
    const int srow = lane >> 3, kch = lane & 7;

    f32x4 acc[4][4];
#pragma unroll
    for (int i_ = 0; i_ < 4; ++i_)
#pragma unroll
        for (int j_ = 0; j_ < 4; ++j_) acc[i_][j_] = fzero();

#define STAGE_TRI(b, k0)                                                          \
    {                                                                             \
        _Pragma("unroll")                                                         \
        for (int q = 0; q < 4; ++q) {                                             \
            const int rowb = w * 32 + q * 8;                                      \
            const int ra = rowb + srow;                                           \
            const int sc = (kch ^ (ra & 7)) * 8;                                  \
            async16(&sA[b][rowb * 64], Lc + (size_t)ra * NRES + (k0) + sc);       \
            async16(&sB[b][rowb * 64], Rc + (size_t)ra * NRES + (k0) + sc);       \
        }                                                                         \
    }

    STAGE_TRI(0, 0)
    __syncthreads();

    int cur = 0;
#pragma unroll 1
    for (int it = 0; it < 12; ++it) {
        if (it < 11) STAGE_TRI(cur ^ 1, (it + 1) * 64)
#pragma unroll
        for (int kk = 0; kk < 2; ++kk) {
            bf16x8 a[4], b[4];
#pragma unroll
            for (int f = 0; f < 4; ++f) {
                const int rowa = wm * 64 + f * 16 + l15;
                const int rowbb = wn * 64 + f * 16 + l15;
                a[f] = *(const bf16x8*)&sA[cur][rowa * 64 + (((kk * 4 + l4) ^ (rowa & 7)) << 3)];
                b[f] = *(const bf16x8*)&sB[cur][rowbb * 64 + (((kk * 4 + l4) ^ (rowbb & 7)) << 3)];
            }
#pragma unroll
            for (int fm = 0; fm < 4; ++fm)
#pragma unroll
                for (int fn = 0; fn < 4; ++fn)
                    acc[fm][fn] = __builtin_amdgcn_mfma_f32_16x16x32_bf16(a[fm], b[fn], acc[fm][fn], 0, 0, 0);
        }
        __syncthreads();
        cur ^= 1;
    }

#pragma unroll
    for (int fm = 0; fm < 4; ++fm)
#pragma unroll
        for (int fn = 0; fn < 4; ++fn) {
            const int col = tj * 128 + wn * 64 + fn * 16 + l15;
#pragma unroll
            for (int r = 0; r < 4; ++r) {
                const int row = ti * 128 + wm * 64 + fm * 16 + l4 * 4 + r;
                Tc[(size_t)row * NRES + col] = f2bf(acc[fm][fn][r]);
            }
        }
}

// ---------------------------------------------------------------------------
// Kernel C: per-pixel LN over c of tri, out-projection MFMA, gate, f32 out.
// Block = 128 pixels (one i, 128 consecutive j), 256 threads.
__global__ void __launch_bounds__(256)
k_final(const unsigned short* __restrict__ tri,
        const unsigned short* __restrict__ gate_t,
        const float* __restrict__ cnw, const float* __restrict__ cnb,
        const unsigned short* __restrict__ Wout, const float* __restrict__ ob,
        float* __restrict__ out) {
    __shared__ unsigned short sT[128 * 136];  // [c][j], 8-elem XOR swizzle on j
    __shared__ unsigned short sX[128 * 128];  // LN'd, [j][c], byte XOR swizzle
    __shared__ float sS[2][128], sQ[2][128], sMu[128], sRs[128];

    const int t = threadIdx.x, lane = t & 63, w = t >> 6;
    const int i = blockIdx.x / 6;
    const int j0 = (blockIdx.x % 6) * 128;
    const size_t pixbase = (size_t)i * NRES + j0;

    // load tri[c][i][j0..j0+128) -> sT
    {
        const int c = t >> 1, jseg = (t & 1) * 64;
        const unsigned short* src = tri + (size_t)c * NPIX + pixbase + jseg;
        const int cx = (c & 7) << 3;
#pragma unroll
        for (int q = 0; q < 8; ++q) {
            uint4 v = *(const uint4*)(src + q * 8);
            *(uint4*)&sT[c * 136 + ((jseg + q * 8) ^ cx)] = v;
        }
    }
    __syncthreads();
    {
        const int j = t & 127, h = t >> 7;
        float s = 0.f, s2 = 0.f;
#pragma unroll
        for (int cc = 0; cc < 64; ++cc) {
            const int c = h * 64 + cc;
            const float v = bf2f(sT[c * 136 + (j ^ ((c & 7) << 3))]);
            s += v; s2 += v * v;
        }
        sS[h][j] = s; sQ[h][j] = s2;
    }
    __syncthreads();
    if (t < 128) {
        const float s = sS[0][t] + sS[1][t];
        const float s2 = sQ[0][t] + sQ[1][t];
        const float mu = s * (1.f / 128.f);
        sMu[t] = mu;
        sRs[t] = rsqrtf(s2 * (1.f / 128.f) - mu * mu + 1e-5f);
    }
    __syncthreads();
    {
        const int j = t >> 1, cs = (t & 1) * 64;
        const float mu = sMu[j], rs = sRs[j];
#pragma unroll
        for (int cc = 0; cc < 64; cc += 2) {
            const int c0 = cs + cc, c1 = c0 + 1;
            const float v0 = (bf2f(sT[c0 * 136 + (j ^ ((c0 & 7) << 3))]) - mu) * rs * cnw[c0] + cnb[c0];
            const float v1 = (bf2f(sT[c1 * 136 + (j ^ ((c1 & 7) << 3))]) - mu) * rs * cnw[c1] + cnb[c1];
            const unsigned pk = (unsigned)f2bf(v0) | ((unsigned)f2bf(v1) << 16);
            int byte = j * 256 + c0 * 2;  byte ^= (j & 7) << 4;
            *(unsigned*)((char*)sX + byte) = pk;
        }
    }
    __syncthreads();

    const int wm = w >> 1, wn = w & 1;
    const int l15 = lane & 15, l4 = lane >> 4;
    f32x4 acc[4][4];
#pragma unroll
    for (int i_ = 0; i_ < 4; ++i_)
#pragma unroll
        for (int j_ = 0; j_ < 4; ++j_) acc[i_][j_] = fzero();

#pragma unroll
    for (int kk = 0; kk < 4; ++kk) {
        const int kb = kk * 32 + l4 * 8;
        bf16x8 a[4], b[4];
#pragma unroll
        for (int f = 0; f < 4; ++f) {
            const int row = wm * 64 + f * 16 + l15;
            int byte = row * 256 + kb * 2;  byte ^= (row & 7) << 4;
            a[f] = *(const bf16x8*)((const char*)sX + byte);
            b[f] = *(const bf16x8*)(Wout + (size_t)(wn * 64 + f * 16 + l15) * CZ + kb);
        }
#pragma unroll
        for (int fm = 0; fm < 4; ++fm)
#pragma unroll
            for (int fn = 0; fn < 4; ++fn)
                acc[fm][fn] = __builtin_amdgcn_mfma_f32_16x16x32_bf16(a[fm], b[fn], acc[fm][fn], 0, 0, 0);
    }
#pragma unroll
    for (int fm = 0; fm < 4; ++fm)
#pragma unroll
        for (int fn = 0; fn < 4; ++fn) {
            const int o = wn * 64 + fn * 16 + l15;
            const float bo = ob[o];
            const u64 gv = *(const u64*)&gate_t[(size_t)o * NPIX + pixbase + wm * 64 + fm * 16 + l4 * 4];
#pragma unroll
            for (int r = 0; r < 4; ++r) {
                const int j = wm * 64 + fm * 16 + l4 * 4 + r;
                const size_t m = pixbase + j;
                out[m * CZ + o] = (acc[fm][fn][r] + bo) * bf2f((unsigned short)(gv >> (16 * r)));
            }
        }
}

// ---------------------------------------------------------------------------
extern "C" void kernel_launch(void* const* d_in, const int* in_sizes, int n_in,
                              void* d_out, int out_size, void* d_ws, size_t ws_size,
                              hipStream_t stream) {
    (void)in_sizes; (void)n_in; (void)out_size; (void)ws_size;
    const float* act  = (const float*)d_in[0];
    const float* mask = (const float*)d_in[1];
    const float* lnw  = (const float*)d_in[2];
    const float* lnb  = (const float*)d_in[3];
    const float* pw   = (const float*)d_in[4];
    const float* pb   = (const float*)d_in[5];
    const float* gw   = (const float*)d_in[6];
    const float* gb   = (const float*)d_in[7];
    const float* cnw  = (const float*)d_in[8];
    const float* cnb  = (const float*)d_in[9];
    const float* ow   = (const float*)d_in[10];
    const float* ob   = (const float*)d_in[11];
    const float* glw  = (const float*)d_in[12];
    const float* glb  = (const float*)d_in[13];

    char* ws = (char*)d_ws;
    size_t off = 0;
    unsigned short* left_t  = (unsigned short*)(ws + off); off += (size_t)128 * NPIX * 2;
    unsigned short* right_t = (unsigned short*)(ws + off); off += (size_t)128 * NPIX * 2;
    unsigned short* gate_t  = (unsigned short*)(ws + off); off += (size_t)128 * NPIX * 2;
    unsigned short* tribuf  = (unsigned short*)(ws + off); off += (size_t)128 * NPIX * 2;  // actln, then tri
    unsigned short* Wcat    = (unsigned short*)(ws + off); off += 640 * 128 * 2;
    unsigned short* Wout    = (unsigned short*)(ws + off); off += 128 * 128 * 2;
    float* bcat             = (float*)(ws + off);          off += 640 * 4;
    // total ws use: ~604.2 MB

    k_pack<<<320, 256, 0, stream>>>(pw, gw, glw, pb, gb, glb, ow, Wcat, bcat, Wout);
    k_ln<<<NPIX / 64, 256, 0, stream>>>(act, lnw, lnb, tribuf);
    k_proj<<<(NPIX / 32) * 3, 256, 0, stream>>>(tribuf, mask, Wcat, bcat,
                                                left_t, right_t, gate_t);
    k_tri<<<128 * 36, 256, 0, stream>>>(left_t, right_t, tribuf);
    k_final<<<NRES * 6, 256, 0, stream>>>(tribuf, gate_t, cnw, cnb, Wout, ob, (float*)d_out);
}